// Round 1
// baseline (359.992 us; speedup 1.0000x reference)
//
#include <hip/hip_runtime.h>

typedef unsigned short ushort_t;
typedef __attribute__((ext_vector_type(8))) short short8;
typedef __attribute__((ext_vector_type(4))) float f32x4;

// ---- bf16 helpers (RNE) ----
__device__ __forceinline__ ushort_t f2bf(float x) {
  union { float f; unsigned u; } v; v.f = x;
  unsigned r = v.u + 0x7fffu + ((v.u >> 16) & 1u);
  return (ushort_t)(r >> 16);
}
__device__ __forceinline__ float bf2f(ushort_t h) {
  union { unsigned u; float f; } v; v.u = ((unsigned)h) << 16;
  return v.f;
}

// ---- async global->LDS, 16B per lane, wave-uniform LDS base ----
__device__ __forceinline__ void async_cp16(const ushort_t* g, ushort_t* lds) {
  __builtin_amdgcn_global_load_lds(
      (const __attribute__((address_space(1))) unsigned int*)g,
      (__attribute__((address_space(3))) unsigned int*)lds, 16, 0, 0);
}

// =====================================================================
// NT GEMM core: C[m][n] = sum_k A[m][k]*B[n][k], bf16 in, fp32 acc.
// Tile MT x NT, K-chunk BKT (32/64/128), 256 threads = 4 waves (2x2).
// EPI 1: store bf16 C to Cb.
// EPI 2: v = tan(acc * ip[row] * ic[col]); dual f32 store Cf0, Cf1.
// =====================================================================
template <int MT, int NT, int BKT, int EPI>
__device__ __forceinline__ void gemm_core(
    const ushort_t* __restrict__ A, int lda,
    const ushort_t* __restrict__ B, int ldb,
    int K,
    ushort_t* sA, ushort_t* sB,
    ushort_t* Cb, float* Cf0, float* Cf1, int ldc,
    const float* __restrict__ ip, const float* __restrict__ ic) {
  constexpr int MI = MT / 32, NI = NT / 32, KU = BKT / 32;
  constexpr int LPR = BKT / 8;    // lanes per staged row
  constexpr int RPC = 256 / LPR;  // rows per cp16 call
  const int t = threadIdx.x;
  const int wave = t >> 6, lane = t & 63;
  const int lm = lane & 15, lq = lane >> 4;
  const int wr = wave >> 1, wc = wave & 1;

  f32x4 acc[MI][NI] = {};

  const ushort_t* ga = A + (size_t)(t / LPR) * lda + (t % LPR) * 8;
  const ushort_t* gb = B + (size_t)(t / LPR) * ldb + (t % LPR) * 8;
  ushort_t* sA0 = sA + wave * 512;  // wave-uniform base; lane-linear t*8
  ushort_t* sB0 = sB + wave * 512;

  for (int k0 = 0; k0 < K; k0 += BKT) {
#pragma unroll
    for (int j = 0; j < MT / RPC; j++)
      async_cp16(ga + k0 + (size_t)j * RPC * lda, sA0 + j * 2048);
#pragma unroll
    for (int j = 0; j < NT / RPC; j++)
      async_cp16(gb + k0 + (size_t)j * RPC * ldb, sB0 + j * 2048);
    __syncthreads();  // drains vmcnt before s_barrier

#pragma unroll
    for (int ku = 0; ku < KU; ku++) {
      short8 af[MI], bf4[NI];
#pragma unroll
      for (int i = 0; i < MI; i++)
        af[i] = *(const short8*)(sA + (wr * (MT / 2) + i * 16 + lm) * BKT +
                                 ku * 32 + lq * 8);
#pragma unroll
      for (int i = 0; i < NI; i++)
        bf4[i] = *(const short8*)(sB + (wc * (NT / 2) + i * 16 + lm) * BKT +
                                  ku * 32 + lq * 8);
#pragma unroll
      for (int mt = 0; mt < MI; mt++)
#pragma unroll
        for (int nt = 0; nt < NI; nt++)
          acc[mt][nt] = __builtin_amdgcn_mfma_f32_16x16x32_bf16(
              af[mt], bf4[nt], acc[mt][nt], 0, 0, 0);
    }
    __syncthreads();
  }

  // C/D layout (verified m89/m91): col = lane&15, row = (lane>>4)*4 + reg
#pragma unroll
  for (int mt = 0; mt < MI; mt++) {
    int rb = wr * (MT / 2) + mt * 16 + lq * 4;
#pragma unroll
    for (int nt = 0; nt < NI; nt++) {
      int c = wc * (NT / 2) + nt * 16 + lm;
#pragma unroll
      for (int r = 0; r < 4; r++) {
        size_t idx = (size_t)(rb + r) * ldc + c;
        if (EPI == 1) {
          Cb[idx] = f2bf(acc[mt][nt][r]);
        } else {
          float v = __tanf(acc[mt][nt][r] * ip[rb + r] * ic[c]);
          Cf0[idx] = v;
          Cf1[idx] = v;
        }
      }
    }
  }
}

// =====================================================================
// convT: 64x64 tile, read f32, write bf16 straight + bf16 transposed
// =====================================================================
__global__ __launch_bounds__(256) void convT(
    const float* __restrict__ in, ushort_t* __restrict__ outn,
    ushort_t* __restrict__ outt, int n) {
  __shared__ float tile[64][65];
  const int t = threadIdx.x;
  const int r0 = blockIdx.y * 64, c0 = blockIdx.x * 64;
  const int cr = t >> 4;        // 0..15
  const int cc = (t & 15) * 4;  // 0..60
#pragma unroll
  for (int p = 0; p < 4; p++) {
    int r = cr + p * 16;
    float4 v = *(const float4*)(in + (size_t)(r0 + r) * n + c0 + cc);
    tile[r][cc + 0] = v.x; tile[r][cc + 1] = v.y;
    tile[r][cc + 2] = v.z; tile[r][cc + 3] = v.w;
    ushort4 o;
    o.x = f2bf(v.x); o.y = f2bf(v.y); o.z = f2bf(v.z); o.w = f2bf(v.w);
    *(ushort4*)(outn + (size_t)(r0 + r) * n + c0 + cc) = o;
  }
  __syncthreads();
#pragma unroll
  for (int p = 0; p < 4; p++) {
    int r = cr + p * 16;  // output row = c0 + r
    ushort4 o;
    o.x = f2bf(tile[cc + 0][r]); o.y = f2bf(tile[cc + 1][r]);
    o.z = f2bf(tile[cc + 2][r]); o.w = f2bf(tile[cc + 3][r]);
    *(ushort4*)(outt + (size_t)(c0 + r) * n + r0 + cc) = o;
  }
}

// =====================================================================
// xcvt: concat(pre,cur) f32 [8192x512] -> bf16 xbf, 8 elems/thread
// =====================================================================
__global__ __launch_bounds__(256) void xcvt(
    const float* __restrict__ pre, const float* __restrict__ cur,
    ushort_t* __restrict__ xbf) {
  const size_t i = ((size_t)blockIdx.x * 256 + threadIdx.x) * 8;
  const float* src =
      (i < (size_t)4096 * 512) ? (pre + i) : (cur + (i - (size_t)4096 * 512));
  float4 a = *(const float4*)(src);
  float4 b = *(const float4*)(src + 4);
  short8 o;
  o[0] = (short)f2bf(a.x); o[1] = (short)f2bf(a.y);
  o[2] = (short)f2bf(a.z); o[3] = (short)f2bf(a.w);
  o[4] = (short)f2bf(b.x); o[5] = (short)f2bf(b.y);
  o[6] = (short)f2bf(b.z); o[7] = (short)f2bf(b.w);
  *(short8*)(xbf + i) = o;
}

// =====================================================================
// K1: pw_t[512 x 8192] = (concat(pre,cur) @ w)^T as NT GEMM.
// A = wt_t bf16 (64-row slice), B = xbf bf16 (128-row slice), BK=64.
// Pure global_load_lds staging on both operands (no in-loop f32 convert).
// =====================================================================
__global__ __launch_bounds__(256) void k1_gemm(
    const ushort_t* __restrict__ wt_t, const ushort_t* __restrict__ xbf,
    ushort_t* __restrict__ pw_t) {
  __shared__ __align__(16) ushort_t sA[64 * 64];
  __shared__ __align__(16) ushort_t sB[128 * 64];
  const int bm = blockIdx.x & 7, bn = blockIdx.x >> 3;
  const ushort_t* A = wt_t + (size_t)bm * 64 * 512;
  const ushort_t* B = xbf + (size_t)bn * 128 * 512;
  ushort_t* C = pw_t + (size_t)bm * 64 * 8192 + bn * 128;
  gemm_core<64, 128, 64, 1>(A, 512, B, 512, 512, sA, sB, C, nullptr, nullptr,
                            8192, nullptr, nullptr);
}

// =====================================================================
// K2 fused: half0 pre_h = adj @ cur_w ; half1 cur_h = adj^T @ pre_w
// 128x64 tiles, BK=128 (half the barrier drains vs BK=64; LDS 48KB,
// occupancy is grid-limited at 2 blocks/CU so no loss), 512 blocks.
// =====================================================================
__global__ __launch_bounds__(256) void k2_gemm(
    const ushort_t* __restrict__ adj, const ushort_t* __restrict__ adj_t,
    const ushort_t* __restrict__ pw_t, ushort_t* __restrict__ pn) {
  __shared__ __align__(16) ushort_t sA[128 * 128];
  __shared__ __align__(16) ushort_t sB[64 * 128];
  const int b = blockIdx.x;
  const int half = b >> 8, bb = b & 255;
  const int bn = (bb >> 3) & 7;
  const int bm = (bb & 7) | ((bb >> 6) << 3);
  const ushort_t* A = (half ? adj_t : adj) + (size_t)bm * 128 * 4096;
  const ushort_t* B = pw_t + (size_t)bn * 64 * 8192 + (half ? 0 : 4096);
  ushort_t* C = pn + (half ? (size_t)4096 * 512 : 0) +
                (size_t)bm * 128 * 512 + bn * 64;
  gemm_core<128, 64, 128, 1>(A, 4096, B, 8192, 4096, sA, sB, C, nullptr,
                             nullptr, 512, nullptr, nullptr);
}

// =====================================================================
// invnorm: invn[row] = 1 / max(||pn[row]||, 1e-8), one wave per row
// =====================================================================
__global__ __launch_bounds__(256) void invnorm_kernel(
    const ushort_t* __restrict__ pn, float* __restrict__ invn) {
  const int t = threadIdx.x;
  const int wave = t >> 6, lane = t & 63;
  const size_t row = (size_t)blockIdx.x * 4 + wave;
  const ushort_t* p = pn + row * 512 + lane * 8;
  short8 v = *(const short8*)p;
  float s = 0.f;
#pragma unroll
  for (int i = 0; i < 8; i++) {
    float f = bf2f((ushort_t)v[i]);
    s += f * f;
  }
#pragma unroll
  for (int off = 32; off > 0; off >>= 1) s += __shfl_xor(s, off, 64);
  if (lane == 0) invn[row] = 1.0f / fmaxf(sqrtf(s), 1e-8f);
}

// =====================================================================
// K3: cos = (pre_h @ cur_h^T) * inv_i * inv_j, tan, dual f32 store.
// 128x128, BK=64 (8 iters instead of 16; LDS 32KB keeps 4 blocks/CU),
// 1024 blocks.
// =====================================================================
__global__ __launch_bounds__(256) void k3_gemm(
    const ushort_t* __restrict__ pn, const float* __restrict__ invn,
    float* __restrict__ out) {
  __shared__ __align__(16) ushort_t sA[128 * 64];
  __shared__ __align__(16) ushort_t sB[128 * 64];
  const int bm = blockIdx.x & 31, bn = blockIdx.x >> 5;
  const ushort_t* A = pn + (size_t)bm * 128 * 512;
  const ushort_t* B = pn + (size_t)4096 * 512 + (size_t)bn * 128 * 512;
  float* C0 = out + (size_t)bm * 128 * 4096 + bn * 128;
  gemm_core<128, 128, 64, 2>(A, 512, B, 512, 512, sA, sB, nullptr, C0,
                             C0 + (size_t)4096 * 4096, 4096,
                             invn + bm * 128, invn + 4096 + bn * 128);
}

// =====================================================================
extern "C" void kernel_launch(void* const* d_in, const int* in_sizes, int n_in,
                              void* d_out, int out_size, void* d_ws,
                              size_t ws_size, hipStream_t stream) {
  const float* pre = (const float*)d_in[0];   // [4096,512] f32
  const float* cur = (const float*)d_in[1];   // [4096,512] f32
  const float* adj = (const float*)d_in[2];   // [4096,4096] f32
  const float* wt  = (const float*)d_in[3];   // [512,512] f32
  float* out = (float*)d_out;                 // 2 x [4096,4096] f32

  // workspace layout (~93 MB)
  ushort_t* adj_bf = (ushort_t*)d_ws;                       // 4096*4096
  ushort_t* adj_t  = adj_bf + (size_t)4096 * 4096;          // 4096*4096
  ushort_t* pw_t   = adj_t + (size_t)4096 * 4096;           // 512*8192
  ushort_t* pn     = pw_t + (size_t)512 * 8192;             // 8192*512
  ushort_t* wt_t   = pn + (size_t)8192 * 512;               // 512*512
  ushort_t* wt_bf  = wt_t + (size_t)512 * 512;              // 512*512 (dummy)
  float*    invn   = (float*)(wt_bf + (size_t)512 * 512);   // 8192 f32
  ushort_t* xbf    = (ushort_t*)(invn + 8192);              // 8192*512

  convT<<<dim3(64, 64), 256, 0, stream>>>(adj, adj_bf, adj_t, 4096);
  convT<<<dim3(8, 8), 256, 0, stream>>>(wt, wt_bf, wt_t, 512);
  xcvt<<<2048, 256, 0, stream>>>(pre, cur, xbf);
  k1_gemm<<<512, 256, 0, stream>>>(wt_t, xbf, pw_t);
  k2_gemm<<<512, 256, 0, stream>>>(adj_bf, adj_t, pw_t, pn);
  invnorm_kernel<<<2048, 256, 0, stream>>>(pn, invn);
  k3_gemm<<<1024, 256, 0, stream>>>(pn, invn, out);
}

// Round 2
// 306.996 us; speedup vs baseline: 1.1726x; 1.1726x over previous
//
#include <hip/hip_runtime.h>

typedef unsigned short ushort_t;
typedef __attribute__((ext_vector_type(8))) short short8;
typedef __attribute__((ext_vector_type(4))) float f32x4;

// ---- bf16 helpers (RNE) ----
__device__ __forceinline__ ushort_t f2bf(float x) {
  union { float f; unsigned u; } v; v.f = x;
  unsigned r = v.u + 0x7fffu + ((v.u >> 16) & 1u);
  return (ushort_t)(r >> 16);
}
__device__ __forceinline__ float bf2f(ushort_t h) {
  union { unsigned u; float f; } v; v.u = ((unsigned)h) << 16;
  return v.f;
}

// ---- async global->LDS, 16B per lane, wave-uniform LDS base ----
__device__ __forceinline__ void async_cp16(const ushort_t* g, ushort_t* lds) {
  __builtin_amdgcn_global_load_lds(
      (const __attribute__((address_space(1))) unsigned int*)g,
      (__attribute__((address_space(3))) unsigned int*)lds, 16, 0, 0);
}

// =====================================================================
// NT GEMM core: C[m][n] = sum_k A[m][k]*B[n][k], bf16 in, fp32 acc.
// Tile MT x NT, K-chunk BKT (64/128), 256 threads = 4 waves (2x2).
//
// LDS XOR swizzle (rule 21, both-sides): LDS[row][seg] = G[row][seg^(row&7)]
// where seg = 16B segment within a row. Staging keeps the LDS dest linear
// (global_load_lds requirement) and pre-swizzles the per-lane GLOBAL source
// (valid: RPC % 8 == 0 so row&7 is per-lane constant). Fragment reads XOR
// the segment with lm&7 (valid: row = base + lm with base % 8 == 0).
// This takes the quarter-wave ds_read_b128 from 16-way to 2-way conflicts.
//
// EPI 1: store bf16 C to Cb.
// EPI 2: v = tan(acc * ip[row] * ic[col]); dual f32 store Cf0, Cf1.
// =====================================================================
template <int MT, int NT, int BKT, int EPI>
__device__ __forceinline__ void gemm_core(
    const ushort_t* __restrict__ A, int lda,
    const ushort_t* __restrict__ B, int ldb,
    int K,
    ushort_t* sA, ushort_t* sB,
    ushort_t* Cb, float* Cf0, float* Cf1, int ldc,
    const float* __restrict__ ip, const float* __restrict__ ic) {
  constexpr int MI = MT / 32, NI = NT / 32, KU = BKT / 32;
  constexpr int LPR = BKT / 8;    // lanes (16B segs) per staged row
  constexpr int RPC = 256 / LPR;  // rows per cp16 call (mult of 8)
  static_assert(RPC % 8 == 0, "row&7 must be per-lane constant");
  const int t = threadIdx.x;
  const int wave = t >> 6, lane = t & 63;
  const int lm = lane & 15, lq = lane >> 4;
  const int wr = wave >> 1, wc = wave & 1;

  f32x4 acc[MI][NI] = {};

  // swizzled global source: lane t covers (row = t/LPR, seg = t%LPR) of the
  // linear LDS chunk; fetch global segment seg ^ (row&7).
  const int srow = t / LPR;
  const int gseg = (t % LPR) ^ (srow & 7);
  const ushort_t* ga = A + (size_t)srow * lda + gseg * 8;
  const ushort_t* gb = B + (size_t)srow * ldb + gseg * 8;
  ushort_t* sA0 = sA + wave * 512;  // wave-uniform base; lane-linear t*8
  ushort_t* sB0 = sB + wave * 512;

  const int sw = lm & 7;  // row&7 for fragment reads

  for (int k0 = 0; k0 < K; k0 += BKT) {
#pragma unroll
    for (int j = 0; j < MT / RPC; j++)
      async_cp16(ga + k0 + (size_t)j * RPC * lda, sA0 + j * 2048);
#pragma unroll
    for (int j = 0; j < NT / RPC; j++)
      async_cp16(gb + k0 + (size_t)j * RPC * ldb, sB0 + j * 2048);
    __syncthreads();  // drains vmcnt before s_barrier

#pragma unroll
    for (int ku = 0; ku < KU; ku++) {
      short8 af[MI], bf4[NI];
#pragma unroll
      for (int i = 0; i < MI; i++)
        af[i] = *(const short8*)(sA + (wr * (MT / 2) + i * 16 + lm) * BKT +
                                 ((ku * 4 + lq) ^ sw) * 8);
#pragma unroll
      for (int i = 0; i < NI; i++)
        bf4[i] = *(const short8*)(sB + (wc * (NT / 2) + i * 16 + lm) * BKT +
                                  ((ku * 4 + lq) ^ sw) * 8);
#pragma unroll
      for (int mt = 0; mt < MI; mt++)
#pragma unroll
        for (int nt = 0; nt < NI; nt++)
          acc[mt][nt] = __builtin_amdgcn_mfma_f32_16x16x32_bf16(
              af[mt], bf4[nt], acc[mt][nt], 0, 0, 0);
    }
    __syncthreads();
  }

  // C/D layout (verified m89/m91): col = lane&15, row = (lane>>4)*4 + reg
#pragma unroll
  for (int mt = 0; mt < MI; mt++) {
    int rb = wr * (MT / 2) + mt * 16 + lq * 4;
#pragma unroll
    for (int nt = 0; nt < NI; nt++) {
      int c = wc * (NT / 2) + nt * 16 + lm;
#pragma unroll
      for (int r = 0; r < 4; r++) {
        size_t idx = (size_t)(rb + r) * ldc + c;
        if (EPI == 1) {
          Cb[idx] = f2bf(acc[mt][nt][r]);
        } else {
          float v = __tanf(acc[mt][nt][r] * ip[rb + r] * ic[c]);
          Cf0[idx] = v;
          Cf1[idx] = v;
        }
      }
    }
  }
}

// =====================================================================
// convT: 64x64 tile, read f32, write bf16 straight + bf16 transposed
// =====================================================================
__global__ __launch_bounds__(256) void convT(
    const float* __restrict__ in, ushort_t* __restrict__ outn,
    ushort_t* __restrict__ outt, int n) {
  __shared__ float tile[64][65];
  const int t = threadIdx.x;
  const int r0 = blockIdx.y * 64, c0 = blockIdx.x * 64;
  const int cr = t >> 4;        // 0..15
  const int cc = (t & 15) * 4;  // 0..60
#pragma unroll
  for (int p = 0; p < 4; p++) {
    int r = cr + p * 16;
    float4 v = *(const float4*)(in + (size_t)(r0 + r) * n + c0 + cc);
    tile[r][cc + 0] = v.x; tile[r][cc + 1] = v.y;
    tile[r][cc + 2] = v.z; tile[r][cc + 3] = v.w;
    ushort4 o;
    o.x = f2bf(v.x); o.y = f2bf(v.y); o.z = f2bf(v.z); o.w = f2bf(v.w);
    *(ushort4*)(outn + (size_t)(r0 + r) * n + c0 + cc) = o;
  }
  __syncthreads();
#pragma unroll
  for (int p = 0; p < 4; p++) {
    int r = cr + p * 16;  // output row = c0 + r
    ushort4 o;
    o.x = f2bf(tile[cc + 0][r]); o.y = f2bf(tile[cc + 1][r]);
    o.z = f2bf(tile[cc + 2][r]); o.w = f2bf(tile[cc + 3][r]);
    *(ushort4*)(outt + (size_t)(c0 + r) * n + r0 + cc) = o;
  }
}

// =====================================================================
// xcvt: concat(pre,cur) f32 [8192x512] -> bf16 xbf, 8 elems/thread
// =====================================================================
__global__ __launch_bounds__(256) void xcvt(
    const float* __restrict__ pre, const float* __restrict__ cur,
    ushort_t* __restrict__ xbf) {
  const size_t i = ((size_t)blockIdx.x * 256 + threadIdx.x) * 8;
  const float* src =
      (i < (size_t)4096 * 512) ? (pre + i) : (cur + (i - (size_t)4096 * 512));
  float4 a = *(const float4*)(src);
  float4 b = *(const float4*)(src + 4);
  short8 o;
  o[0] = (short)f2bf(a.x); o[1] = (short)f2bf(a.y);
  o[2] = (short)f2bf(a.z); o[3] = (short)f2bf(a.w);
  o[4] = (short)f2bf(b.x); o[5] = (short)f2bf(b.y);
  o[6] = (short)f2bf(b.z); o[7] = (short)f2bf(b.w);
  *(short8*)(xbf + i) = o;
}

// =====================================================================
// K1: pw_t[512 x 8192] = (concat(pre,cur) @ w)^T as NT GEMM.
// A = wt_t bf16 (64-row slice), B = xbf bf16 (128-row slice), BK=64.
// =====================================================================
__global__ __launch_bounds__(256) void k1_gemm(
    const ushort_t* __restrict__ wt_t, const ushort_t* __restrict__ xbf,
    ushort_t* __restrict__ pw_t) {
  __shared__ __align__(16) ushort_t sA[64 * 64];
  __shared__ __align__(16) ushort_t sB[128 * 64];
  const int bm = blockIdx.x & 7, bn = blockIdx.x >> 3;
  const ushort_t* A = wt_t + (size_t)bm * 64 * 512;
  const ushort_t* B = xbf + (size_t)bn * 128 * 512;
  ushort_t* C = pw_t + (size_t)bm * 64 * 8192 + bn * 128;
  gemm_core<64, 128, 64, 1>(A, 512, B, 512, 512, sA, sB, C, nullptr, nullptr,
                            8192, nullptr, nullptr);
}

// =====================================================================
// K2 fused: half0 pre_h = adj @ cur_w ; half1 cur_h = adj^T @ pre_w
// 128x64 tiles, BK=128, 512 blocks (2/CU, grid-limited occupancy).
// =====================================================================
__global__ __launch_bounds__(256) void k2_gemm(
    const ushort_t* __restrict__ adj, const ushort_t* __restrict__ adj_t,
    const ushort_t* __restrict__ pw_t, ushort_t* __restrict__ pn) {
  __shared__ __align__(16) ushort_t sA[128 * 128];
  __shared__ __align__(16) ushort_t sB[64 * 128];
  const int b = blockIdx.x;
  const int half = b >> 8, bb = b & 255;
  const int bn = (bb >> 3) & 7;
  const int bm = (bb & 7) | ((bb >> 6) << 3);
  const ushort_t* A = (half ? adj_t : adj) + (size_t)bm * 128 * 4096;
  const ushort_t* B = pw_t + (size_t)bn * 64 * 8192 + (half ? 0 : 4096);
  ushort_t* C = pn + (half ? (size_t)4096 * 512 : 0) +
                (size_t)bm * 128 * 512 + bn * 64;
  gemm_core<128, 64, 128, 1>(A, 4096, B, 8192, 4096, sA, sB, C, nullptr,
                             nullptr, 512, nullptr, nullptr);
}

// =====================================================================
// invnorm: invn[row] = 1 / max(||pn[row]||, 1e-8), one wave per row
// =====================================================================
__global__ __launch_bounds__(256) void invnorm_kernel(
    const ushort_t* __restrict__ pn, float* __restrict__ invn) {
  const int t = threadIdx.x;
  const int wave = t >> 6, lane = t & 63;
  const size_t row = (size_t)blockIdx.x * 4 + wave;
  const ushort_t* p = pn + row * 512 + lane * 8;
  short8 v = *(const short8*)p;
  float s = 0.f;
#pragma unroll
  for (int i = 0; i < 8; i++) {
    float f = bf2f((ushort_t)v[i]);
    s += f * f;
  }
#pragma unroll
  for (int off = 32; off > 0; off >>= 1) s += __shfl_xor(s, off, 64);
  if (lane == 0) invn[row] = 1.0f / fmaxf(sqrtf(s), 1e-8f);
}

// =====================================================================
// K3: cos = (pre_h @ cur_h^T) * inv_i * inv_j, tan, dual f32 store.
// 128x128, BK=64, 1024 blocks (4/CU).
// =====================================================================
__global__ __launch_bounds__(256) void k3_gemm(
    const ushort_t* __restrict__ pn, const float* __restrict__ invn,
    float* __restrict__ out) {
  __shared__ __align__(16) ushort_t sA[128 * 64];
  __shared__ __align__(16) ushort_t sB[128 * 64];
  const int bm = blockIdx.x & 31, bn = blockIdx.x >> 5;
  const ushort_t* A = pn + (size_t)bm * 128 * 512;
  const ushort_t* B = pn + (size_t)4096 * 512 + (size_t)bn * 128 * 512;
  float* C0 = out + (size_t)bm * 128 * 4096 + bn * 128;
  gemm_core<128, 128, 64, 2>(A, 512, B, 512, 512, sA, sB, nullptr, C0,
                             C0 + (size_t)4096 * 4096, 4096,
                             invn + bm * 128, invn + 4096 + bn * 128);
}

// =====================================================================
extern "C" void kernel_launch(void* const* d_in, const int* in_sizes, int n_in,
                              void* d_out, int out_size, void* d_ws,
                              size_t ws_size, hipStream_t stream) {
  const float* pre = (const float*)d_in[0];   // [4096,512] f32
  const float* cur = (const float*)d_in[1];   // [4096,512] f32
  const float* adj = (const float*)d_in[2];   // [4096,4096] f32
  const float* wt  = (const float*)d_in[3];   // [512,512] f32
  float* out = (float*)d_out;                 // 2 x [4096,4096] f32

  // workspace layout (~93 MB)
  ushort_t* adj_bf = (ushort_t*)d_ws;                       // 4096*4096
  ushort_t* adj_t  = adj_bf + (size_t)4096 * 4096;          // 4096*4096
  ushort_t* pw_t   = adj_t + (size_t)4096 * 4096;           // 512*8192
  ushort_t* pn     = pw_t + (size_t)512 * 8192;             // 8192*512
  ushort_t* wt_t   = pn + (size_t)8192 * 512;               // 512*512
  ushort_t* wt_bf  = wt_t + (size_t)512 * 512;              // 512*512 (dummy)
  float*    invn   = (float*)(wt_bf + (size_t)512 * 512);   // 8192 f32
  ushort_t* xbf    = (ushort_t*)(invn + 8192);              // 8192*512

  convT<<<dim3(64, 64), 256, 0, stream>>>(adj, adj_bf, adj_t, 4096);
  convT<<<dim3(8, 8), 256, 0, stream>>>(wt, wt_bf, wt_t, 512);
  xcvt<<<2048, 256, 0, stream>>>(pre, cur, xbf);
  k1_gemm<<<512, 256, 0, stream>>>(wt_t, xbf, pw_t);
  k2_gemm<<<512, 256, 0, stream>>>(adj_bf, adj_t, pw_t, pn);
  invnorm_kernel<<<2048, 256, 0, stream>>>(pn, invn);
  k3_gemm<<<1024, 256, 0, stream>>>(pn, invn, out);
}

// Round 3
// 304.512 us; speedup vs baseline: 1.1822x; 1.0082x over previous
//
#include <hip/hip_runtime.h>

typedef unsigned short ushort_t;
typedef __attribute__((ext_vector_type(8))) short short8;
typedef __attribute__((ext_vector_type(4))) float f32x4;

// ---- bf16 helpers (RNE) ----
__device__ __forceinline__ ushort_t f2bf(float x) {
  union { float f; unsigned u; } v; v.f = x;
  unsigned r = v.u + 0x7fffu + ((v.u >> 16) & 1u);
  return (ushort_t)(r >> 16);
}
__device__ __forceinline__ float bf2f(ushort_t h) {
  union { unsigned u; float f; } v; v.u = ((unsigned)h) << 16;
  return v.f;
}

// ---- async global->LDS, 16B per lane, wave-uniform LDS base ----
__device__ __forceinline__ void async_cp16(const ushort_t* g, ushort_t* lds) {
  __builtin_amdgcn_global_load_lds(
      (const __attribute__((address_space(1))) unsigned int*)g,
      (__attribute__((address_space(3))) unsigned int*)lds, 16, 0, 0);
}

// =====================================================================
// NT GEMM core: C[m][n] = sum_k A[m][k]*B[n][k], bf16 in, fp32 acc.
// Tile MT x NT, K-chunk BKT (64/128), 256 threads = 4 waves (2x2).
//
// LDS XOR swizzle (rule 21, both-sides): LDS[row][seg] = G[row][seg^(row&7)]
// staged with linear LDS dest + pre-swizzled per-lane GLOBAL source;
// fragment reads XOR the segment with lm&7. Conflict-free (verified r2:
// SQ_LDS_BANK_CONFLICT 4.4e7 -> ~0, total -53us).
//
// EPI 1: store bf16 C to Cb.
// EPI 2: v = tan(acc * ip[row] * ic[col]); dual f32 store Cf0, Cf1.
// =====================================================================
template <int MT, int NT, int BKT, int EPI>
__device__ __forceinline__ void gemm_core(
    const ushort_t* __restrict__ A, int lda,
    const ushort_t* __restrict__ B, int ldb,
    int K,
    ushort_t* sA, ushort_t* sB,
    ushort_t* Cb, float* Cf0, float* Cf1, int ldc,
    const float* __restrict__ ip, const float* __restrict__ ic) {
  constexpr int MI = MT / 32, NI = NT / 32, KU = BKT / 32;
  constexpr int LPR = BKT / 8;    // lanes (16B segs) per staged row
  constexpr int RPC = 256 / LPR;  // rows per cp16 call (mult of 8)
  static_assert(RPC % 8 == 0, "row&7 must be per-lane constant");
  const int t = threadIdx.x;
  const int wave = t >> 6, lane = t & 63;
  const int lm = lane & 15, lq = lane >> 4;
  const int wr = wave >> 1, wc = wave & 1;

  f32x4 acc[MI][NI] = {};

  const int srow = t / LPR;
  const int gseg = (t % LPR) ^ (srow & 7);
  const ushort_t* ga = A + (size_t)srow * lda + gseg * 8;
  const ushort_t* gb = B + (size_t)srow * ldb + gseg * 8;
  ushort_t* sA0 = sA + wave * 512;  // wave-uniform base; lane-linear t*8
  ushort_t* sB0 = sB + wave * 512;

  const int sw = lm & 7;  // row&7 for fragment reads

  for (int k0 = 0; k0 < K; k0 += BKT) {
#pragma unroll
    for (int j = 0; j < MT / RPC; j++)
      async_cp16(ga + k0 + (size_t)j * RPC * lda, sA0 + j * 2048);
#pragma unroll
    for (int j = 0; j < NT / RPC; j++)
      async_cp16(gb + k0 + (size_t)j * RPC * ldb, sB0 + j * 2048);
    __syncthreads();  // drains vmcnt before s_barrier

#pragma unroll
    for (int ku = 0; ku < KU; ku++) {
      short8 af[MI], bf4[NI];
#pragma unroll
      for (int i = 0; i < MI; i++)
        af[i] = *(const short8*)(sA + (wr * (MT / 2) + i * 16 + lm) * BKT +
                                 ((ku * 4 + lq) ^ sw) * 8);
#pragma unroll
      for (int i = 0; i < NI; i++)
        bf4[i] = *(const short8*)(sB + (wc * (NT / 2) + i * 16 + lm) * BKT +
                                  ((ku * 4 + lq) ^ sw) * 8);
#pragma unroll
      for (int mt = 0; mt < MI; mt++)
#pragma unroll
        for (int nt = 0; nt < NI; nt++)
          acc[mt][nt] = __builtin_amdgcn_mfma_f32_16x16x32_bf16(
              af[mt], bf4[nt], acc[mt][nt], 0, 0, 0);
    }
    __syncthreads();
  }

  // C/D layout (verified m89/m91): col = lane&15, row = (lane>>4)*4 + reg
#pragma unroll
  for (int mt = 0; mt < MI; mt++) {
    int rb = wr * (MT / 2) + mt * 16 + lq * 4;
#pragma unroll
    for (int nt = 0; nt < NI; nt++) {
      int c = wc * (NT / 2) + nt * 16 + lm;
#pragma unroll
      for (int r = 0; r < 4; r++) {
        size_t idx = (size_t)(rb + r) * ldc + c;
        if (EPI == 1) {
          Cb[idx] = f2bf(acc[mt][nt][r]);
        } else {
          float v = __tanf(acc[mt][nt][r] * ip[rb + r] * ic[c]);
          Cf0[idx] = v;
          Cf1[idx] = v;
        }
      }
    }
  }
}

// =====================================================================
// convT: 64x64 tile, read f32, write bf16 straight + bf16 transposed
// =====================================================================
__global__ __launch_bounds__(256) void convT(
    const float* __restrict__ in, ushort_t* __restrict__ outn,
    ushort_t* __restrict__ outt, int n) {
  __shared__ float tile[64][65];
  const int t = threadIdx.x;
  const int r0 = blockIdx.y * 64, c0 = blockIdx.x * 64;
  const int cr = t >> 4;        // 0..15
  const int cc = (t & 15) * 4;  // 0..60
#pragma unroll
  for (int p = 0; p < 4; p++) {
    int r = cr + p * 16;
    float4 v = *(const float4*)(in + (size_t)(r0 + r) * n + c0 + cc);
    tile[r][cc + 0] = v.x; tile[r][cc + 1] = v.y;
    tile[r][cc + 2] = v.z; tile[r][cc + 3] = v.w;
    ushort4 o;
    o.x = f2bf(v.x); o.y = f2bf(v.y); o.z = f2bf(v.z); o.w = f2bf(v.w);
    *(ushort4*)(outn + (size_t)(r0 + r) * n + c0 + cc) = o;
  }
  __syncthreads();
#pragma unroll
  for (int p = 0; p < 4; p++) {
    int r = cr + p * 16;  // output row = c0 + r
    ushort4 o;
    o.x = f2bf(tile[cc + 0][r]); o.y = f2bf(tile[cc + 1][r]);
    o.z = f2bf(tile[cc + 2][r]); o.w = f2bf(tile[cc + 3][r]);
    *(ushort4*)(outt + (size_t)(c0 + r) * n + r0 + cc) = o;
  }
}

// =====================================================================
// xcvt: concat(pre,cur) f32 [8192x512] -> bf16 xbf, 8 elems/thread
// =====================================================================
__global__ __launch_bounds__(256) void xcvt(
    const float* __restrict__ pre, const float* __restrict__ cur,
    ushort_t* __restrict__ xbf) {
  const size_t i = ((size_t)blockIdx.x * 256 + threadIdx.x) * 8;
  const float* src =
      (i < (size_t)4096 * 512) ? (pre + i) : (cur + (i - (size_t)4096 * 512));
  float4 a = *(const float4*)(src);
  float4 b = *(const float4*)(src + 4);
  short8 o;
  o[0] = (short)f2bf(a.x); o[1] = (short)f2bf(a.y);
  o[2] = (short)f2bf(a.z); o[3] = (short)f2bf(a.w);
  o[4] = (short)f2bf(b.x); o[5] = (short)f2bf(b.y);
  o[6] = (short)f2bf(b.z); o[7] = (short)f2bf(b.w);
  *(short8*)(xbf + i) = o;
}

// =====================================================================
// K1: pw_t[512 x 8192] = (concat(pre,cur) @ w)^T as NT GEMM.
// =====================================================================
__global__ __launch_bounds__(256) void k1_gemm(
    const ushort_t* __restrict__ wt_t, const ushort_t* __restrict__ xbf,
    ushort_t* __restrict__ pw_t) {
  __shared__ __align__(16) ushort_t sA[64 * 64];
  __shared__ __align__(16) ushort_t sB[128 * 64];
  const int bm = blockIdx.x & 7, bn = blockIdx.x >> 3;
  const ushort_t* A = wt_t + (size_t)bm * 64 * 512;
  const ushort_t* B = xbf + (size_t)bn * 128 * 512;
  ushort_t* C = pw_t + (size_t)bm * 64 * 8192 + bn * 128;
  gemm_core<64, 128, 64, 1>(A, 512, B, 512, 512, sA, sB, C, nullptr, nullptr,
                            8192, nullptr, nullptr);
}

// =====================================================================
// K2 fused: half0 pre_h = adj @ cur_w ; half1 cur_h = adj^T @ pre_w
// 128x64 tiles, BK=128, 512 blocks (2/CU).
// XCD-grouped mapping: xcd = b&7 owns an 8bm x 8bn x 1half sub-grid;
// all 64 of its blocks are co-resident (32 CU x 2), so A/B panel reuse
// is served by the XCD's private L2 (sliding ~0.4MB K-window) instead
// of re-pulling ~768MB through Infinity Cache.
// =====================================================================
__global__ __launch_bounds__(256) void k2_gemm(
    const ushort_t* __restrict__ adj, const ushort_t* __restrict__ adj_t,
    const ushort_t* __restrict__ pw_t, ushort_t* __restrict__ pn) {
  __shared__ __align__(16) ushort_t sA[128 * 128];
  __shared__ __align__(16) ushort_t sB[64 * 128];
  const int b = blockIdx.x;
  const int xcd = b & 7, i = b >> 3;            // i in 0..63
  const int half = xcd & 1;
  const int bm = ((xcd >> 1) << 3) | (i & 7);   // 0..31
  const int bn = i >> 3;                        // 0..7
  const ushort_t* A = (half ? adj_t : adj) + (size_t)bm * 128 * 4096;
  const ushort_t* B = pw_t + (size_t)bn * 64 * 8192 + (half ? 0 : 4096);
  ushort_t* C = pn + (half ? (size_t)4096 * 512 : 0) +
                (size_t)bm * 128 * 512 + bn * 64;
  gemm_core<128, 64, 128, 1>(A, 4096, B, 8192, 4096, sA, sB, C, nullptr,
                             nullptr, 512, nullptr, nullptr);
}

// =====================================================================
// invnorm: invn[row] = 1 / max(||pn[row]||, 1e-8), one wave per row
// =====================================================================
__global__ __launch_bounds__(256) void invnorm_kernel(
    const ushort_t* __restrict__ pn, float* __restrict__ invn) {
  const int t = threadIdx.x;
  const int wave = t >> 6, lane = t & 63;
  const size_t row = (size_t)blockIdx.x * 4 + wave;
  const ushort_t* p = pn + row * 512 + lane * 8;
  short8 v = *(const short8*)p;
  float s = 0.f;
#pragma unroll
  for (int i = 0; i < 8; i++) {
    float f = bf2f((ushort_t)v[i]);
    s += f * f;
  }
#pragma unroll
  for (int off = 32; off > 0; off >>= 1) s += __shfl_xor(s, off, 64);
  if (lane == 0) invn[row] = 1.0f / fmaxf(sqrtf(s), 1e-8f);
}

// =====================================================================
// K3: cos = (pre_h @ cur_h^T) * inv_i * inv_j, tan, dual f32 store.
// 128x128, BK=64, 1024 blocks (4/CU).
// XCD-grouped mapping: xcd = b&7 owns 4bm x 32bn; its 128 blocks are
// co-resident (32 CU x 4). A panels (0.5MB) pin in L2; B half streamed
// once per XCD (~36MB LLC total vs 512MB before).
// =====================================================================
__global__ __launch_bounds__(256) void k3_gemm(
    const ushort_t* __restrict__ pn, const float* __restrict__ invn,
    float* __restrict__ out) {
  __shared__ __align__(16) ushort_t sA[128 * 64];
  __shared__ __align__(16) ushort_t sB[128 * 64];
  const int b = blockIdx.x;
  const int xcd = b & 7, i = b >> 3;        // i in 0..127
  const int bm = (xcd << 2) | (i & 3);      // 0..31
  const int bn = i >> 2;                    // 0..31
  const ushort_t* A = pn + (size_t)bm * 128 * 512;
  const ushort_t* B = pn + (size_t)4096 * 512 + (size_t)bn * 128 * 512;
  float* C0 = out + (size_t)bm * 128 * 4096 + bn * 128;
  gemm_core<128, 128, 64, 2>(A, 512, B, 512, 512, sA, sB, nullptr, C0,
                             C0 + (size_t)4096 * 4096, 4096,
                             invn + bm * 128, invn + 4096 + bn * 128);
}

// =====================================================================
extern "C" void kernel_launch(void* const* d_in, const int* in_sizes, int n_in,
                              void* d_out, int out_size, void* d_ws,
                              size_t ws_size, hipStream_t stream) {
  const float* pre = (const float*)d_in[0];   // [4096,512] f32
  const float* cur = (const float*)d_in[1];   // [4096,512] f32
  const float* adj = (const float*)d_in[2];   // [4096,4096] f32
  const float* wt  = (const float*)d_in[3];   // [512,512] f32
  float* out = (float*)d_out;                 // 2 x [4096,4096] f32

  // workspace layout (~93 MB)
  ushort_t* adj_bf = (ushort_t*)d_ws;                       // 4096*4096
  ushort_t* adj_t  = adj_bf + (size_t)4096 * 4096;          // 4096*4096
  ushort_t* pw_t   = adj_t + (size_t)4096 * 4096;           // 512*8192
  ushort_t* pn     = pw_t + (size_t)512 * 8192;             // 8192*512
  ushort_t* wt_t   = pn + (size_t)8192 * 512;               // 512*512
  ushort_t* wt_bf  = wt_t + (size_t)512 * 512;              // 512*512 (dummy)
  float*    invn   = (float*)(wt_bf + (size_t)512 * 512);   // 8192 f32
  ushort_t* xbf    = (ushort_t*)(invn + 8192);              // 8192*512

  convT<<<dim3(64, 64), 256, 0, stream>>>(adj, adj_bf, adj_t, 4096);
  convT<<<dim3(8, 8), 256, 0, stream>>>(wt, wt_bf, wt_t, 512);
  xcvt<<<2048, 256, 0, stream>>>(pre, cur, xbf);
  k1_gemm<<<512, 256, 0, stream>>>(wt_t, xbf, pw_t);
  k2_gemm<<<512, 256, 0, stream>>>(adj_bf, adj_t, pw_t, pn);
  invnorm_kernel<<<2048, 256, 0, stream>>>(pn, invn);
  k3_gemm<<<1024, 256, 0, stream>>>(pn, invn, out);
}

// Round 4
// 301.047 us; speedup vs baseline: 1.1958x; 1.0115x over previous
//
#include <hip/hip_runtime.h>

typedef unsigned short ushort_t;
typedef __attribute__((ext_vector_type(8))) short short8;
typedef __attribute__((ext_vector_type(4))) float f32x4;

// ---- bf16 helpers (RNE) ----
__device__ __forceinline__ ushort_t f2bf(float x) {
  union { float f; unsigned u; } v; v.f = x;
  unsigned r = v.u + 0x7fffu + ((v.u >> 16) & 1u);
  return (ushort_t)(r >> 16);
}
__device__ __forceinline__ float bf2f(ushort_t h) {
  union { unsigned u; float f; } v; v.u = ((unsigned)h) << 16;
  return v.f;
}

// ---- async global->LDS, 16B per lane, wave-uniform LDS base ----
__device__ __forceinline__ void async_cp16(const ushort_t* g, ushort_t* lds) {
  __builtin_amdgcn_global_load_lds(
      (const __attribute__((address_space(1))) unsigned int*)g,
      (__attribute__((address_space(3))) unsigned int*)lds, 16, 0, 0);
}

// =====================================================================
// NT GEMM core: C[m][n] = sum_k A[m][k]*B[n][k], bf16 in, fp32 acc.
// Tile MT x NT, K-chunk BKT (64/128), 256 threads = 4 waves (2x2).
//
// LDS XOR swizzle (rule 21, both-sides): LDS[row][seg] = G[row][seg^(row&7)]
// staged with linear LDS dest + pre-swizzled per-lane GLOBAL source;
// fragment reads XOR the segment with lm&7. Conflict-free (verified r2:
// SQ_LDS_BANK_CONFLICT 4.4e7 -> ~0, total -53us).
//
// EPI 1: store bf16 C to Cb.
// EPI 2: v = tan(acc * ip[row] * ic[col]); dual f32 store Cf0, Cf1.
// =====================================================================
template <int MT, int NT, int BKT, int EPI>
__device__ __forceinline__ void gemm_core(
    const ushort_t* __restrict__ A, int lda,
    const ushort_t* __restrict__ B, int ldb,
    int K,
    ushort_t* sA, ushort_t* sB,
    ushort_t* Cb, float* Cf0, float* Cf1, int ldc,
    const float* __restrict__ ip, const float* __restrict__ ic) {
  constexpr int MI = MT / 32, NI = NT / 32, KU = BKT / 32;
  constexpr int LPR = BKT / 8;    // lanes (16B segs) per staged row
  constexpr int RPC = 256 / LPR;  // rows per cp16 call (mult of 8)
  static_assert(RPC % 8 == 0, "row&7 must be per-lane constant");
  const int t = threadIdx.x;
  const int wave = t >> 6, lane = t & 63;
  const int lm = lane & 15, lq = lane >> 4;
  const int wr = wave >> 1, wc = wave & 1;

  f32x4 acc[MI][NI] = {};

  const int srow = t / LPR;
  const int gseg = (t % LPR) ^ (srow & 7);
  const ushort_t* ga = A + (size_t)srow * lda + gseg * 8;
  const ushort_t* gb = B + (size_t)srow * ldb + gseg * 8;
  ushort_t* sA0 = sA + wave * 512;  // wave-uniform base; lane-linear t*8
  ushort_t* sB0 = sB + wave * 512;

  const int sw = lm & 7;  // row&7 for fragment reads

  for (int k0 = 0; k0 < K; k0 += BKT) {
#pragma unroll
    for (int j = 0; j < MT / RPC; j++)
      async_cp16(ga + k0 + (size_t)j * RPC * lda, sA0 + j * 2048);
#pragma unroll
    for (int j = 0; j < NT / RPC; j++)
      async_cp16(gb + k0 + (size_t)j * RPC * ldb, sB0 + j * 2048);
    __syncthreads();  // drains vmcnt before s_barrier

#pragma unroll
    for (int ku = 0; ku < KU; ku++) {
      short8 af[MI], bf4[NI];
#pragma unroll
      for (int i = 0; i < MI; i++)
        af[i] = *(const short8*)(sA + (wr * (MT / 2) + i * 16 + lm) * BKT +
                                 ((ku * 4 + lq) ^ sw) * 8);
#pragma unroll
      for (int i = 0; i < NI; i++)
        bf4[i] = *(const short8*)(sB + (wc * (NT / 2) + i * 16 + lm) * BKT +
                                  ((ku * 4 + lq) ^ sw) * 8);
#pragma unroll
      for (int mt = 0; mt < MI; mt++)
#pragma unroll
        for (int nt = 0; nt < NI; nt++)
          acc[mt][nt] = __builtin_amdgcn_mfma_f32_16x16x32_bf16(
              af[mt], bf4[nt], acc[mt][nt], 0, 0, 0);
    }
    __syncthreads();
  }

  // C/D layout (verified m89/m91): col = lane&15, row = (lane>>4)*4 + reg
#pragma unroll
  for (int mt = 0; mt < MI; mt++) {
    int rb = wr * (MT / 2) + mt * 16 + lq * 4;
#pragma unroll
    for (int nt = 0; nt < NI; nt++) {
      int c = wc * (NT / 2) + nt * 16 + lm;
#pragma unroll
      for (int r = 0; r < 4; r++) {
        size_t idx = (size_t)(rb + r) * ldc + c;
        if (EPI == 1) {
          Cb[idx] = f2bf(acc[mt][nt][r]);
        } else {
          float v = __tanf(acc[mt][nt][r] * ip[rb + r] * ic[c]);
          Cf0[idx] = v;
          Cf1[idx] = v;
        }
      }
    }
  }
}

// =====================================================================
// convT: 64x64 tile, read f32, write bf16 straight + bf16 transposed
// =====================================================================
__global__ __launch_bounds__(256) void convT(
    const float* __restrict__ in, ushort_t* __restrict__ outn,
    ushort_t* __restrict__ outt, int n) {
  __shared__ float tile[64][65];
  const int t = threadIdx.x;
  const int r0 = blockIdx.y * 64, c0 = blockIdx.x * 64;
  const int cr = t >> 4;        // 0..15
  const int cc = (t & 15) * 4;  // 0..60
#pragma unroll
  for (int p = 0; p < 4; p++) {
    int r = cr + p * 16;
    float4 v = *(const float4*)(in + (size_t)(r0 + r) * n + c0 + cc);
    tile[r][cc + 0] = v.x; tile[r][cc + 1] = v.y;
    tile[r][cc + 2] = v.z; tile[r][cc + 3] = v.w;
    ushort4 o;
    o.x = f2bf(v.x); o.y = f2bf(v.y); o.z = f2bf(v.z); o.w = f2bf(v.w);
    *(ushort4*)(outn + (size_t)(r0 + r) * n + c0 + cc) = o;
  }
  __syncthreads();
#pragma unroll
  for (int p = 0; p < 4; p++) {
    int r = cr + p * 16;  // output row = c0 + r
    ushort4 o;
    o.x = f2bf(tile[cc + 0][r]); o.y = f2bf(tile[cc + 1][r]);
    o.z = f2bf(tile[cc + 2][r]); o.w = f2bf(tile[cc + 3][r]);
    *(ushort4*)(outt + (size_t)(c0 + r) * n + r0 + cc) = o;
  }
}

// =====================================================================
// xcvt: concat(pre,cur) f32 [8192x512] -> bf16 xbf, 8 elems/thread
// =====================================================================
__global__ __launch_bounds__(256) void xcvt(
    const float* __restrict__ pre, const float* __restrict__ cur,
    ushort_t* __restrict__ xbf) {
  const size_t i = ((size_t)blockIdx.x * 256 + threadIdx.x) * 8;
  const float* src =
      (i < (size_t)4096 * 512) ? (pre + i) : (cur + (i - (size_t)4096 * 512));
  float4 a = *(const float4*)(src);
  float4 b = *(const float4*)(src + 4);
  short8 o;
  o[0] = (short)f2bf(a.x); o[1] = (short)f2bf(a.y);
  o[2] = (short)f2bf(a.z); o[3] = (short)f2bf(a.w);
  o[4] = (short)f2bf(b.x); o[5] = (short)f2bf(b.y);
  o[6] = (short)f2bf(b.z); o[7] = (short)f2bf(b.w);
  *(short8*)(xbf + i) = o;
}

// =====================================================================
// K1: pw_t[512 x 8192] = (concat(pre,cur) @ w)^T as NT GEMM.
// =====================================================================
__global__ __launch_bounds__(256) void k1_gemm(
    const ushort_t* __restrict__ wt_t, const ushort_t* __restrict__ xbf,
    ushort_t* __restrict__ pw_t) {
  __shared__ __align__(16) ushort_t sA[64 * 64];
  __shared__ __align__(16) ushort_t sB[128 * 64];
  const int bm = blockIdx.x & 7, bn = blockIdx.x >> 3;
  const ushort_t* A = wt_t + (size_t)bm * 64 * 512;
  const ushort_t* B = xbf + (size_t)bn * 128 * 512;
  ushort_t* C = pw_t + (size_t)bm * 64 * 8192 + bn * 128;
  gemm_core<64, 128, 64, 1>(A, 512, B, 512, 512, sA, sB, C, nullptr, nullptr,
                            8192, nullptr, nullptr);
}

// =====================================================================
// K2 fused: half0 pre_h = adj @ cur_w ; half1 cur_h = adj^T @ pre_w
// 128x64 tiles, BK=128, 512 blocks (2/CU).
// =====================================================================
__global__ __launch_bounds__(256) void k2_gemm(
    const ushort_t* __restrict__ adj, const ushort_t* __restrict__ adj_t,
    const ushort_t* __restrict__ pw_t, ushort_t* __restrict__ pn) {
  __shared__ __align__(16) ushort_t sA[128 * 128];
  __shared__ __align__(16) ushort_t sB[64 * 128];
  const int b = blockIdx.x;
  const int xcd = b & 7, i = b >> 3;            // i in 0..63
  const int half = xcd & 1;
  const int bm = ((xcd >> 1) << 3) | (i & 7);   // 0..31
  const int bn = i >> 3;                        // 0..7
  const ushort_t* A = (half ? adj_t : adj) + (size_t)bm * 128 * 4096;
  const ushort_t* B = pw_t + (size_t)bn * 64 * 8192 + (half ? 0 : 4096);
  ushort_t* C = pn + (half ? (size_t)4096 * 512 : 0) +
                (size_t)bm * 128 * 512 + bn * 64;
  gemm_core<128, 64, 128, 1>(A, 4096, B, 8192, 4096, sA, sB, C, nullptr,
                             nullptr, 512, nullptr, nullptr);
}

// =====================================================================
// invnorm: invn[row] = 1 / max(||pn[row]||, 1e-8), one wave per row
// =====================================================================
__global__ __launch_bounds__(256) void invnorm_kernel(
    const ushort_t* __restrict__ pn, float* __restrict__ invn) {
  const int t = threadIdx.x;
  const int wave = t >> 6, lane = t & 63;
  const size_t row = (size_t)blockIdx.x * 4 + wave;
  const ushort_t* p = pn + row * 512 + lane * 8;
  short8 v = *(const short8*)p;
  float s = 0.f;
#pragma unroll
  for (int i = 0; i < 8; i++) {
    float f = bf2f((ushort_t)v[i]);
    s += f * f;
  }
#pragma unroll
  for (int off = 32; off > 0; off >>= 1) s += __shfl_xor(s, off, 64);
  if (lane == 0) invn[row] = 1.0f / fmaxf(sqrtf(s), 1e-8f);
}

// =====================================================================
// K3: cos = (pre_h @ cur_h^T) * inv_i * inv_j, tan, dual f32 store.
// 256x128 tile, BK=64, 512 blocks (2/CU via __launch_bounds__(256,2)).
// Wave region 128x64 (MI=8 x NI=4): ds_read per MFMA 0.375KB (-25%),
// staging per FLOP -43%, drains per FLOP halved vs 128x128.
// =====================================================================
__global__ __launch_bounds__(256, 2) void k3_gemm(
    const ushort_t* __restrict__ pn, const float* __restrict__ invn,
    float* __restrict__ out) {
  __shared__ __align__(16) ushort_t sA[256 * 64];
  __shared__ __align__(16) ushort_t sB[128 * 64];
  const int bm = blockIdx.x & 15;   // 0..15  (M / 256)
  const int bn = blockIdx.x >> 4;   // 0..31  (N / 128)
  const ushort_t* A = pn + (size_t)bm * 256 * 512;
  const ushort_t* B = pn + (size_t)4096 * 512 + (size_t)bn * 128 * 512;
  float* C0 = out + (size_t)bm * 256 * 4096 + bn * 128;
  gemm_core<256, 128, 64, 2>(A, 512, B, 512, 512, sA, sB, nullptr, C0,
                             C0 + (size_t)4096 * 4096, 4096,
                             invn + bm * 256, invn + 4096 + bn * 128);
}

// =====================================================================
extern "C" void kernel_launch(void* const* d_in, const int* in_sizes, int n_in,
                              void* d_out, int out_size, void* d_ws,
                              size_t ws_size, hipStream_t stream) {
  const float* pre = (const float*)d_in[0];   // [4096,512] f32
  const float* cur = (const float*)d_in[1];   // [4096,512] f32
  const float* adj = (const float*)d_in[2];   // [4096,4096] f32
  const float* wt  = (const float*)d_in[3];   // [512,512] f32
  float* out = (float*)d_out;                 // 2 x [4096,4096] f32

  // workspace layout (~93 MB)
  ushort_t* adj_bf = (ushort_t*)d_ws;                       // 4096*4096
  ushort_t* adj_t  = adj_bf + (size_t)4096 * 4096;          // 4096*4096
  ushort_t* pw_t   = adj_t + (size_t)4096 * 4096;           // 512*8192
  ushort_t* pn     = pw_t + (size_t)512 * 8192;             // 8192*512
  ushort_t* wt_t   = pn + (size_t)8192 * 512;               // 512*512
  ushort_t* wt_bf  = wt_t + (size_t)512 * 512;              // 512*512 (dummy)
  float*    invn   = (float*)(wt_bf + (size_t)512 * 512);   // 8192 f32
  ushort_t* xbf    = (ushort_t*)(invn + 8192);              // 8192*512

  convT<<<dim3(64, 64), 256, 0, stream>>>(adj, adj_bf, adj_t, 4096);
  convT<<<dim3(8, 8), 256, 0, stream>>>(wt, wt_bf, wt_t, 512);
  xcvt<<<2048, 256, 0, stream>>>(pre, cur, xbf);
  k1_gemm<<<512, 256, 0, stream>>>(wt_t, xbf, pw_t);
  k2_gemm<<<512, 256, 0, stream>>>(adj_bf, adj_t, pw_t, pn);
  invnorm_kernel<<<2048, 256, 0, stream>>>(pn, invn);
  k3_gemm<<<512, 256, 0, stream>>>(pn, invn, out);
}